// Round 8
// baseline (2530.063 us; speedup 1.0000x reference)
//
#include <hip/hip_runtime.h>

// Exact DTW, antidiagonal-per-wave structure, G=4 row-split workgroups.
// Lane owns RR=N/(512G) contiguous rows. On diagonal k a lane's RR cells are
// independent (no intra-step chain). Handoff of the slab-bottom value:
//  - lane->lane: __shfl_up at step tail (register dataflow)
//  - wave->wave: LDS ring, wave skew WSK=16 steps => ring write and read are
//    always >=1 barrier apart (barrier every KB=8 steps)
//  - WG->WG: producer (last thread) streams bottom-row values to d_ws with a
//    release-flag per 8 diagonals; consumer's wave 0 prefetches block E+3 each
//    epoch into an LDS ring only wave 0 reads (same-wave program order).
// Out-of-band cells are computed, not masked: y is staged with BIG halos, so
// invalid cells evaluate to >=1e30 and are never selected by min3; all valid
// cells' in-band predecessors are exact (BIG paths only lose the min), so the
// result is bit-exact.

#define N    4096
#define TPB  512
#define KB   8            // steps per barrier epoch
#define WSK  16           // per-wave skew (multiple of KB)
#define RSZ  32           // ring entries (diagonals)
#define BIG  1e30f

template <int G>
__global__ __launch_bounds__(TPB, 2)
void dtw_diag(const float* __restrict__ xg, const float* __restrict__ yg,
              float* __restrict__ out, float* __restrict__ gbuf,
              int* __restrict__ flags) {
    constexpr int RR   = N / (TPB * G);    // rows per lane
    constexpr int RPW  = 64 * RR;          // rows per wave
    constexpr int M    = RPW + 16;         // y halo each side
    constexpr int YSZ  = N + 2 * M;
    constexpr int ROWS = N / G;
    constexpr int SEND =
        (((G - 1) * ROWS + ROWS - 1 + N - 1 + 7 * WSK + 1) + KB - 1) / KB * KB;

    __shared__ float ylds[YSZ + YSZ / 8 + 2];   // pad every 8 words
    __shared__ float ring[7][RSZ];              // wave-boundary rings
    __shared__ float ringG[RSZ];                // WG-boundary ring (wave 0 only)

    const int t = threadIdx.x, lane = t & 63, w = t >> 6, g = blockIdx.x;

    // stage y with BIG halos
    for (int u = t; u < YSZ; u += TPB) {
        const int j = u - M;
        ylds[u + (u >> 3)] = ((unsigned)j < (unsigned)N) ? yg[j] : BIG;
    }
    for (int u = t; u < 7 * RSZ; u += TPB) (&ring[0][0])[u] = BIG;
    if (t < RSZ) ringG[t] = BIG;

    // producer prologue: BIG-fill boundary entries below wave-7's window + flags
    float* gme = nullptr; int* fme = nullptr;
    if (G > 1 && g < G - 1) {
        gme = gbuf + (size_t)g * 8320;
        fme = flags + g * 1024;
        const int klo = g * ROWS + 7 * RPW;     // divisible by 8
        for (int k = t; k < klo; k += TPB) gme[k] = BIG;
        __threadfence();
        for (int b = t; b < (klo >> 3); b += TPB)
            __hip_atomic_store(&fme[b], 1, __ATOMIC_RELAXED, __HIP_MEMORY_SCOPE_AGENT);
    }

    const int i0 = g * ROWS + t * RR;
    float x[RR], d1[RR], d2[RR], yw[RR];
#pragma unroll
    for (int r = 0; r < RR; ++r) { x[r] = xg[i0 + r]; d1[r] = BIG; d2[r] = BIG; }
    float nb1 = BIG;
    float nb2 = (g == 0 && t == 0) ? 0.0f : BIG;   // (0,0): min3(BIG,BIG,0)=0 -> D[0][0]=c

    // wave-active window in s (k = s - WSK*w); -2 extension primes nb via two tails
    const int iwlo  = g * ROWS + w * RPW;
    const int wlo_s = max(iwlo - 2 + WSK * w, 0);
    const int whi_s = iwlo + RPW - 1 + (N - 1) + WSK * w;

    {   // prime y window for first executed step
        const int k0 = wlo_s - WSK * w;
#pragma unroll
        for (int r = 0; r < RR; ++r) {
            const int u = k0 - i0 - r + M;
            yw[r] = ylds[u + (u >> 3)];
        }
    }

    const bool is_pref = (G > 1 && g > 0 && w == 0 && lane < KB);
    const float* gsrc  = (G > 1 && g > 0) ? gbuf + (size_t)(g - 1) * 8320 : gbuf;
    const int* fsrc    = (G > 1 && g > 0) ? flags + (g - 1) * 1024 : flags;
    const int BMAX     = (g * ROWS + N - 2) >> 3;      // last needed boundary block
    const bool is_prod = (G > 1 && g < G - 1 && w == 7 && lane == 63);
    const float* ringsrc = (w > 0) ? &ring[w - 1][0] : &ringG[0];
    const bool lane0_ring = (w > 0) || (G > 1 && g > 0);

    __syncthreads();

    float gv = BIG;
    for (int sb = 0; sb < SEND; sb += KB) {
        // consumer: fetch boundary block E+3 (published to ringG at epoch end;
        // first read 2+ epochs later by this same wave -> program order safe)
        const int pb = (sb >> 3) + 3;
        const bool do_pf = is_pref && pb <= BMAX;
        if (do_pf) {
            while (__hip_atomic_load(&fsrc[pb], __ATOMIC_ACQUIRE,
                                     __HIP_MEMORY_SCOPE_AGENT) == 0) {}
            gv = gsrc[pb * KB + lane];
        }
#pragma unroll
        for (int ph = 0; ph < KB; ++ph) {
            const int s = sb + ph;
            if (s >= wlo_s && s <= whi_s) {          // wave-uniform
                const int k = s - WSK * w;
                // RR independent cells of diagonal k
                float up = nb1, dg = nb2;
#pragma unroll
                for (int r = 0; r < RR; ++r) {
                    const float old = d1[r], odg = d2[r];
                    const float m = fminf(old, fminf(up, dg));
                    const float v = fabsf(x[r] - yw[r]) + m;
                    d2[r] = old; d1[r] = v;
                    up = old; dg = odg;
                }
                const float bot = d1[RR - 1];
                // tail handoff for next step
                const float upn  = __shfl_up(bot, 1);
                const float rsel = ringsrc[k & (RSZ - 1)];   // uniform addr: broadcast
                nb2 = nb1;
                nb1 = (lane == 0) ? (lane0_ring ? rsel : BIG) : upn;
                if (lane == 63 && w < 7) ring[w][k & (RSZ - 1)] = bot;
                if (is_prod) {
                    gme[k] = bot;
                    if (ph == KB - 1)   // k = 7 mod 8 here: block (k-7)/8 complete
                        __hip_atomic_store(&fme[(k - (KB - 1)) >> 3], 1,
                                           __ATOMIC_RELEASE, __HIP_MEMORY_SCOPE_AGENT);
                }
                // slide y window
#pragma unroll
                for (int r = RR - 1; r > 0; --r) yw[r] = yw[r - 1];
                {
                    const int u = k + 1 - i0 + M;
                    yw[0] = ylds[u + (u >> 3)];
                }
            }
            asm volatile("" ::: "memory");   // pin ring op ordering across phases
        }
        if (do_pf) ringG[(pb * KB + lane) & (RSZ - 1)] = gv;
        __syncthreads();
    }

    // producer epilogue: flag the final (partial) boundary block
    if (G > 1 && g < G - 1 && t == TPB - 1)
        __hip_atomic_store(&fme[((g + 1) * ROWS + N - 2) >> 3], 1,
                           __ATOMIC_RELEASE, __HIP_MEMORY_SCOPE_AGENT);
    if (g == G - 1 && t == TPB - 1) out[0] = d1[RR - 1];
}

extern "C" void kernel_launch(void* const* d_in, const int* in_sizes, int n_in,
                              void* d_out, int out_size, void* d_ws, size_t ws_size,
                              hipStream_t stream) {
    const float* src = (const float*)d_in[0];
    const float* tgt = (const float*)d_in[1];
    float* out = (float*)d_out;

    const size_t req = 16384 + 3 * 8320 * sizeof(float);
    if (ws_size >= req) {
        int*   flags = (int*)d_ws;
        float* gbuf  = (float*)((char*)d_ws + 16384);
        hipMemsetAsync(d_ws, 0, 16384, stream);    // fresh flags every call
        hipLaunchKernelGGL((dtw_diag<4>), dim3(4), dim3(TPB), 0, stream,
                           src, tgt, out, gbuf, flags);
    } else {
        hipLaunchKernelGGL((dtw_diag<1>), dim3(1), dim3(TPB), 0, stream,
                           src, tgt, out, (float*)nullptr, (int*)nullptr);
    }
}

// Round 9
// 979.808 us; speedup vs baseline: 2.5822x; 2.5822x over previous
//
#include <hip/hip_runtime.h>

#define N    4096
#define BIG  1e30f

// ================= G=8 single-wave row-split pipeline =================
// WG g owns rows [512g, 512g+512); 64 lanes x RR8=8 rows; C4=4 cols/chunk;
// lane l runs chunk q at step s = l + q (unconditional body, clamped
// addressing; out-of-band cells self-poison to >=1e30 and, by chunk-index
// alignment, only ever feed out-of-band cells). Neighbor handoff lane->lane is
// v_mov_dpp wave_shr:1 whose 'old' operand simultaneously merges lane 0's
// cross-WG ring value. Cross-WG: lane 63 streams bottom cells to gbuf
// (device-scope), flag per 8 chunks; consumer wave prefetches 32-col blocks
// 4 steps ahead into an LDS ring only this wave touches (no barriers at all).

#define C4     4
#define NCH8   (N / C4)          // 1024 chunks
#define RR8    8
#define NWG    8
#define STEPS8 (63 + NCH8)       // 1087
#define NBLK8  (NCH8 / 8)        // 128 blocks (8 chunks = 32 cols each)

#define DPP_SHR1(res, oldv, srcv)                                         \
    res = __int_as_float(__builtin_amdgcn_update_dpp(                     \
        __float_as_int(oldv), __float_as_int(srcv), 0x138, 0xF, 0xF, false));

__global__ __launch_bounds__(64, 1)
void dtw_wavepipe8(const float* __restrict__ xg, const float* __restrict__ yg,
                   float* __restrict__ out, float* __restrict__ gbuf,
                   int* __restrict__ flags) {
    __shared__ float ylds[N];
    __shared__ float slot[4][32];

    const int l = threadIdx.x;
    const int g = blockIdx.x;

    for (int j = l * 4; j < N; j += 256)
        *(float4*)&ylds[j] = *(const float4*)&yg[j];

    float x[RR8], carry[RR8];
    const int i0 = g * (N / NWG) + l * RR8;
#pragma unroll
    for (int r = 0; r < RR8; ++r) { x[r] = xg[i0 + r]; carry[r] = BIG; }

    float bt0 = BIG, bt1 = BIG, bt2 = BIG, bt3 = BIG;
    float nb0, nb1, nb2, nb3;
    float diagc = (g == 0 && l == 0) ? 0.0f : BIG;  // (0,0): min3(BIG,BIG,0)=0 -> D[0][0]=c

    const int gp = (g > 0) ? g - 1 : 0;
    const float* bsrc = gbuf + (size_t)gp * N;
    const int*   bflg = flags + gp * NBLK8;
    float*       bdst = gbuf + (size_t)g * N;
    int*         fdst = flags + g * NBLK8;

    // prologue: consumer fetches boundary block 0 -> slot[0]
    if (g > 0 && l < 32) {
        while (__hip_atomic_load(&bflg[0], __ATOMIC_ACQUIRE,
                                 __HIP_MEMORY_SCOPE_AGENT) == 0) {}
        slot[0][l] = __hip_atomic_load(&bsrc[l], __ATOMIC_RELAXED,
                                       __HIP_MEMORY_SCOPE_AGENT);
    }
    __syncthreads();

    // prime nb (step 0) via the same dpp-merge with bt=BIG
    {
        float4 rv = make_float4(BIG, BIG, BIG, BIG);
        if (g > 0) rv = *(const float4*)&slot[0][0];
        DPP_SHR1(nb0, rv.x, bt0)
        DPP_SHR1(nb1, rv.y, bt1)
        DPP_SHR1(nb2, rv.z, bt2)
        DPP_SHR1(nb3, rv.w, bt3)
    }
    float4 yv = *(const float4*)&ylds[0];   // clamp(0-l)=0 for all lanes

    float pend = 0.0f;

    for (int s = 0; s < STEPS8; ++s) {
        // ---- consumer machinery (s-uniform branches) ----
        if (g > 0) {
            const int ph = s & 7;
            if (ph == 4) {                       // issue block load 4 steps early
                const int m = (s + 4) >> 3;
                if (m < NBLK8 && l < 32) {
                    while (__hip_atomic_load(&bflg[m], __ATOMIC_ACQUIRE,
                                             __HIP_MEMORY_SCOPE_AGENT) == 0) {}
                    pend = __hip_atomic_load(&bsrc[m * 32 + l], __ATOMIC_RELAXED,
                                             __HIP_MEMORY_SCOPE_AGENT);
                }
            } else if (ph == 6) {                // land it 2 steps later
                const int m = (s + 2) >> 3;
                if (m < NBLK8 && l < 32) slot[m & 3][l] = pend;
            }
        }

        // ---- body: chunk q = s - l (clamped addressing, unconditional) ----
        const float yc0 = yv.x, yc1 = yv.y, yc2 = yv.z, yc3 = yv.w;
#define DO_COL(YC, NB, DG, BTOUT)                                         \
        { float up = (NB), dgv = (DG);                                    \
          _Pragma("unroll")                                               \
          for (int r = 0; r < RR8; ++r) {                                 \
              const float old = carry[r];                                 \
              const float v = fabsf(x[r] - (YC)) +                        \
                              fminf(up, fminf(old, dgv));                 \
              carry[r] = v; up = v; dgv = old;                            \
          }                                                               \
          BTOUT = up; }
        DO_COL(yc0, nb0, diagc, bt0)
        DO_COL(yc1, nb1, nb0,   bt1)
        DO_COL(yc2, nb2, nb1,   bt2)
        DO_COL(yc3, nb3, nb2,   bt3)
#undef DO_COL
        diagc = nb3;

        // ---- producer: stream genuine bottom cells, flag per 8 chunks ----
        if (g < NWG - 1) {
            const unsigned q63 = (unsigned)(s - 63);
            if (q63 < (unsigned)NCH8) {
                if (l == 63) {
                    const int col = (int)q63 * C4;
                    __hip_atomic_store(&bdst[col + 0], bt0, __ATOMIC_RELAXED, __HIP_MEMORY_SCOPE_AGENT);
                    __hip_atomic_store(&bdst[col + 1], bt1, __ATOMIC_RELAXED, __HIP_MEMORY_SCOPE_AGENT);
                    __hip_atomic_store(&bdst[col + 2], bt2, __ATOMIC_RELAXED, __HIP_MEMORY_SCOPE_AGENT);
                    __hip_atomic_store(&bdst[col + 3], bt3, __ATOMIC_RELAXED, __HIP_MEMORY_SCOPE_AGENT);
                    if ((q63 & 7u) == 7u)
                        __hip_atomic_store(&fdst[q63 >> 3], 1, __ATOMIC_RELEASE,
                                           __HIP_MEMORY_SCOPE_AGENT);
                }
            }
        }

        // ---- tail: handoff + operand prefetch for step s+1 ----
        {
            float4 rv = make_float4(BIG, BIG, BIG, BIG);
            if (g > 0) {
                const int qn = (s + 1 < NCH8) ? (s + 1) : (NCH8 - 1);
                rv = *(const float4*)&slot[(qn >> 3) & 3][(qn & 7) * C4];
            }
            DPP_SHR1(nb0, rv.x, bt0)
            DPP_SHR1(nb1, rv.y, bt1)
            DPP_SHR1(nb2, rv.z, bt2)
            DPP_SHR1(nb3, rv.w, bt3)
            int qn2 = s + 1 - l;
            qn2 = qn2 < 0 ? 0 : (qn2 > NCH8 - 1 ? NCH8 - 1 : qn2);
            yv = *(const float4*)&ylds[qn2 * C4];
        }
    }

    if (g == NWG - 1 && l == 63) out[0] = carry[RR8 - 1];
}

// ================= fallback: R7 single-WG kernel (proven, 550us) ==========
#define TPB  512
#define C    4
#define NCH  (N / C)
#define KB   8
#define RSZ  32
#define NW   (TPB / 64)
#define BS   (C + 1)
#define YIDX(j) ((j) + (((j) >> 5) << 2))
#define STEPS 1592

__global__ __launch_bounds__(TPB, 1)
void dtw_mw2(const float* __restrict__ xg, const float* __restrict__ yg,
             float* __restrict__ out) {
    __shared__ float ylds[N + (N >> 5) * 4];
    __shared__ float bot[2][TPB * BS];
    __shared__ float ring[NW - 1][RSZ][C];
    __shared__ float big4[C];

    const int t = threadIdx.x, lane = t & 63, w = t >> 6;
    for (int j4 = t * 4; j4 < N; j4 += TPB * 4)
        *(float4*)&ylds[YIDX(j4)] = *(const float4*)&yg[j4];
    if (t < C) big4[t] = BIG;

    constexpr int RRf = N / TPB;
    float x[RRf], carry[RRf];
    const int i0 = t * RRf;
#pragma unroll
    for (int r = 0; r < RRf; ++r) { x[r] = xg[i0 + r]; carry[r] = BIG; }
    float diagc = (t == 0) ? 0.0f : BIG;
    const int start = t + KB * w;
    float nb[C];
#pragma unroll
    for (int k = 0; k < C; ++k) nb[k] = BIG;
    float4 yv = *(const float4*)&ylds[YIDX(0)];
    __syncthreads();

    for (int sb = 0; sb < STEPS; sb += KB) {
        for (int ss = 0; ss < KB; ++ss) {
            const int s = sb + ss;
            const int c = s - start;
            if ((unsigned)c < (unsigned)NCH) {
                float* dst = (lane == 63 && w < NW - 1) ? &ring[w][c & (RSZ - 1)][0]
                                                        : &bot[s & 1][t * BS];
                const float yc[C] = {yv.x, yv.y, yv.z, yv.w};
                float dg = diagc;
#pragma unroll
                for (int k = 0; k < C; ++k) {
                    float up = nb[k], dgv = dg;
#pragma unroll
                    for (int r = 0; r < RRf; ++r) {
                        const float old = carry[r];
                        const float v = fabsf(x[r] - yc[k]) + fminf(up, fminf(old, dgv));
                        carry[r] = v; up = v; dgv = old;
                    }
                    dst[k] = up; dg = nb[k];
                }
                diagc = dg;
            }
            {
                const int c1 = s + 1 - start;
                const bool pf = ((unsigned)c1 < (unsigned)NCH);
                const float* src = (lane == 0)
                    ? ((w == 0) ? big4 : &ring[w - 1][c1 & (RSZ - 1)][0])
                    : &bot[s & 1][(t - 1) * BS];
                float n0 = src[0], n1 = src[1], n2 = src[2], n3 = src[3];
                nb[0] = pf ? n0 : BIG; nb[1] = pf ? n1 : BIG;
                nb[2] = pf ? n2 : BIG; nb[3] = pf ? n3 : BIG;
                const int jc = pf ? c1 * C : 0;
                yv = *(const float4*)&ylds[YIDX(jc)];
            }
            asm volatile("" ::: "memory");
        }
        __syncthreads();
    }
    if (t == TPB - 1) out[0] = carry[RRf - 1];
}

extern "C" void kernel_launch(void* const* d_in, const int* in_sizes, int n_in,
                              void* d_out, int out_size, void* d_ws, size_t ws_size,
                              hipStream_t stream) {
    const float* src = (const float*)d_in[0];
    const float* tgt = (const float*)d_in[1];
    float* out = (float*)d_out;

    const size_t FLAGB = (size_t)NWG * NBLK8 * sizeof(int);     // 4 KB
    const size_t req = FLAGB + (size_t)NWG * N * sizeof(float); // 4KB + 128KB
    if (ws_size >= req) {
        int*   flags = (int*)d_ws;
        float* gbuf  = (float*)((char*)d_ws + FLAGB);
        hipMemsetAsync(d_ws, 0, FLAGB, stream);   // fresh flags every call
        hipLaunchKernelGGL(dtw_wavepipe8, dim3(NWG), dim3(64), 0, stream,
                           src, tgt, out, gbuf, flags);
    } else {
        hipLaunchKernelGGL(dtw_mw2, dim3(1), dim3(TPB), 0, stream,
                           src, tgt, out);
    }
}

// Round 10
// 710.171 us; speedup vs baseline: 3.5626x; 1.3797x over previous
//
#include <hip/hip_runtime.h>

#define N    4096
#define BIG  1e30f

// ============ G=2 row-split, R7-structure WGs (256 thr, 4 waves) ============
// WG g owns rows [2048g, 2048g+2048); thread t owns RR=8 rows; C=4 cols/chunk;
// thread t runs chunk c at step s = t + 8*(t/64) + c.  Intra-WG: R7-proven
// (LDS double-buffer bot, wave-skew rings, barrier every KB=8, tail prefetch,
// pf-masked nb).  Cross-WG: WG0's thread 255 streams bottom-row float4 chunks
// to gbuf with a release flag per 8 chunks; WG1's wave 0 prefetches 32-float
// blocks 2 epochs ahead (issue at phase 0, land in LDS at phase 6 -> global
// latency never exposed); thread 0 of WG1 reads nb from that ring (same-wave
// program order => no barrier needed).

#define TPB2   256
#define C      4
#define NCH    (N / C)            // 1024 chunks
#define KB     8
#define RSZ    32
#define NW2    (TPB2 / 64)        // 4 waves
#define NBLK   (NCH / 8)          // 128 flag blocks (8 chunks = 32 cols)
#define LST2   1304               // (255 + 8*3) + 1024, rounded to mult of KB

__global__ __launch_bounds__(TPB2, 1)
void dtw_split2(const float* __restrict__ xg, const float* __restrict__ yg,
                float* __restrict__ out, float* __restrict__ gbuf,
                int* __restrict__ flags) {
    __shared__ float4 yl4[N / 4];            // 16 KB
    __shared__ float4 bot4[2][TPB2];         // 8 KB
    __shared__ float4 ring4[NW2 - 1][RSZ];   // 1.5 KB
    __shared__ float4 gslot4[4][8];          // 512 B (4 blocks x 8 chunks)

    const int t = threadIdx.x, lane = t & 63, w = t >> 6, g = blockIdx.x;
    constexpr int RR = 8;

    for (int i = t; i < N / 4; i += TPB2) yl4[i] = ((const float4*)yg)[i];

    // consumer prologue: wave 0 of WG1 pulls boundary blocks 0,1
    if (g == 1 && t < 64) {
        const int b = t >> 5;                // 0 or 1
        while (__hip_atomic_load(&flags[b], __ATOMIC_ACQUIRE,
                                 __HIP_MEMORY_SCOPE_AGENT) == 0) {}
        ((float*)gslot4)[t] = gbuf[t];
    }

    float x[RR], carry[RR];
    const int i0 = g * (N / 2) + t * RR;
#pragma unroll
    for (int r = 0; r < RR; ++r) { x[r] = xg[i0 + r]; carry[r] = BIG; }

    float diagc = (g == 0 && t == 0) ? 0.0f : BIG;  // (0,0): min3(BIG,BIG,0)=0
    const int start = t + KB * w;
    const bool lane0_big = (lane == 0 && w == 0 && g == 0);  // row -1: nb always BIG

    __syncthreads();

    // prime operands for step 0
    float4 nb = make_float4(BIG, BIG, BIG, BIG);
    if (g == 1 && t == 0) nb = gslot4[0][0];
    float4 yv = yl4[0];
    float pend = 0.0f;

    for (int sb = 0; sb < LST2; sb += KB) {
        for (int ss = 0; ss < KB; ++ss) {
            const int s = sb + ss;

            // ---- cross-WG consumer machinery (wave-uniform) ----
            if (g == 1 && w == 0) {
                if (ss == 0) {                       // issue block load, 2 epochs early
                    const int m = (s >> 3) + 2;
                    if (m < NBLK && lane < 32) {
                        while (__hip_atomic_load(&flags[m], __ATOMIC_ACQUIRE,
                                                 __HIP_MEMORY_SCOPE_AGENT) == 0) {}
                        pend = gbuf[m * 32 + lane];
                    }
                } else if (ss == 6) {                // land it (load long retired)
                    const int m = (s >> 3) + 2;
                    if (m < NBLK && lane < 32)
                        ((float*)&gslot4[(m & 3)][0])[lane] = pend;
                }
            }

            // ---- body: chunk c = s - start ----
            const int c = s - start;
            if ((unsigned)c < (unsigned)NCH) {
                const float yc[C] = {yv.x, yv.y, yv.z, yv.w};
                const float nbv[C] = {nb.x, nb.y, nb.z, nb.w};
                float bt[C];
                float dg = diagc;
#pragma unroll
                for (int k = 0; k < C; ++k) {
                    float up = nbv[k], dgv = dg;
#pragma unroll
                    for (int r = 0; r < RR; ++r) {
                        const float old = carry[r];
                        const float v = fabsf(x[r] - yc[k]) +
                                        fminf(up, fminf(old, dgv));
                        carry[r] = v; up = v; dgv = old;
                    }
                    bt[k] = up;
                    dg = nbv[k];
                }
                diagc = dg;   // = nbv[C-1]

                const float4 btv = make_float4(bt[0], bt[1], bt[2], bt[3]);
                if (lane == 63 && w < NW2 - 1) ring4[w][c & (RSZ - 1)] = btv;
                else                           bot4[s & 1][t] = btv;

                // producer: WG0's bottom thread streams to gbuf + flags
                if (g == 0 && t == TPB2 - 1) {
                    *(float4*)&gbuf[c * 4] = btv;
                    if ((c & 7) == 7)
                        __hip_atomic_store(&flags[c >> 3], 1, __ATOMIC_RELEASE,
                                           __HIP_MEMORY_SCOPE_AGENT);
                }
            }

            // ---- tail: prefetch nb/y for step s+1 ----
            {
                const int c1 = s + 1 - start;
                const bool pf = ((unsigned)c1 < (unsigned)NCH) && !lane0_big;
                const float4* p = &bot4[s & 1][(t > 0) ? (t - 1) : 0];
                if (lane == 0) {
                    p = (w > 0) ? &ring4[w - 1][c1 & (RSZ - 1)]
                                : &gslot4[(c1 >> 3) & 3][c1 & 7];
                }
                const float4 nbl = *p;
                nb.x = pf ? nbl.x : BIG;
                nb.y = pf ? nbl.y : BIG;
                nb.z = pf ? nbl.z : BIG;
                nb.w = pf ? nbl.w : BIG;
                const int jc = ((unsigned)c1 < (unsigned)NCH) ? c1 : 0;
                yv = yl4[jc];
            }
            asm volatile("" ::: "memory");
        }
        __syncthreads();
    }

    if (g == 1 && t == TPB2 - 1) out[0] = carry[RR - 1];
}

// ================= fallback: R7 single-WG kernel (proven, 550us) ==========
#define TPB  512
#define NCHf (N / C)
#define NW   (TPB / 64)
#define BS   (C + 1)
#define YIDX(j) ((j) + (((j) >> 5) << 2))
#define STEPS 1592

__global__ __launch_bounds__(TPB, 1)
void dtw_mw2(const float* __restrict__ xg, const float* __restrict__ yg,
             float* __restrict__ out) {
    __shared__ float ylds[N + (N >> 5) * 4];
    __shared__ float bot[2][TPB * BS];
    __shared__ float ring[NW - 1][RSZ][C];
    __shared__ float big4[C];

    const int t = threadIdx.x, lane = t & 63, w = t >> 6;
    for (int j4 = t * 4; j4 < N; j4 += TPB * 4)
        *(float4*)&ylds[YIDX(j4)] = *(const float4*)&yg[j4];
    if (t < C) big4[t] = BIG;

    constexpr int RRf = N / TPB;
    float x[RRf], carry[RRf];
    const int i0 = t * RRf;
#pragma unroll
    for (int r = 0; r < RRf; ++r) { x[r] = xg[i0 + r]; carry[r] = BIG; }
    float diagc = (t == 0) ? 0.0f : BIG;
    const int start = t + KB * w;
    float nb[C];
#pragma unroll
    for (int k = 0; k < C; ++k) nb[k] = BIG;
    float4 yv = *(const float4*)&ylds[YIDX(0)];
    __syncthreads();

    for (int sb = 0; sb < STEPS; sb += KB) {
        for (int ss = 0; ss < KB; ++ss) {
            const int s = sb + ss;
            const int c = s - start;
            if ((unsigned)c < (unsigned)NCHf) {
                float* dst = (lane == 63 && w < NW - 1) ? &ring[w][c & (RSZ - 1)][0]
                                                        : &bot[s & 1][t * BS];
                const float yc[C] = {yv.x, yv.y, yv.z, yv.w};
                float dg = diagc;
#pragma unroll
                for (int k = 0; k < C; ++k) {
                    float up = nb[k], dgv = dg;
#pragma unroll
                    for (int r = 0; r < RRf; ++r) {
                        const float old = carry[r];
                        const float v = fabsf(x[r] - yc[k]) + fminf(up, fminf(old, dgv));
                        carry[r] = v; up = v; dgv = old;
                    }
                    dst[k] = up; dg = nb[k];
                }
                diagc = dg;
            }
            {
                const int c1 = s + 1 - start;
                const bool pf = ((unsigned)c1 < (unsigned)NCHf);
                const float* src = (lane == 0)
                    ? ((w == 0) ? big4 : &ring[w - 1][c1 & (RSZ - 1)][0])
                    : &bot[s & 1][(t - 1) * BS];
                float n0 = src[0], n1 = src[1], n2 = src[2], n3 = src[3];
                nb[0] = pf ? n0 : BIG; nb[1] = pf ? n1 : BIG;
                nb[2] = pf ? n2 : BIG; nb[3] = pf ? n3 : BIG;
                const int jc = pf ? c1 * C : 0;
                yv = *(const float4*)&ylds[YIDX(jc)];
            }
            asm volatile("" ::: "memory");
        }
        __syncthreads();
    }
    if (t == TPB - 1) out[0] = carry[RRf - 1];
}

extern "C" void kernel_launch(void* const* d_in, const int* in_sizes, int n_in,
                              void* d_out, int out_size, void* d_ws, size_t ws_size,
                              hipStream_t stream) {
    const float* src = (const float*)d_in[0];
    const float* tgt = (const float*)d_in[1];
    float* out = (float*)d_out;

    const size_t FLAGB = 4096;                                   // 128 flags
    const size_t req = FLAGB + (size_t)N * sizeof(float);        // 4K + 16K
    if (ws_size >= req) {
        int*   flags = (int*)d_ws;
        float* gbuf  = (float*)((char*)d_ws + FLAGB);
        hipMemsetAsync(d_ws, 0, FLAGB, stream);   // fresh flags every call
        hipLaunchKernelGGL(dtw_split2, dim3(2), dim3(TPB2), 0, stream,
                           src, tgt, out, gbuf, flags);
    } else {
        hipLaunchKernelGGL(dtw_mw2, dim3(1), dim3(TPB), 0, stream,
                           src, tgt, out);
    }
}

// Round 11
// 500.400 us; speedup vs baseline: 5.0561x; 1.4192x over previous
//
#include <hip/hip_runtime.h>

// Exact DTW, single workgroup, 8 waves (2/SIMD), R7 sync structure with an
// instruction diet. Thread t owns 8 rows; C=4 cols/chunk; thread t runs chunk
// c at step s = t + 8*(t/64) + c. Intra-wave handoff: LDS double-buffered
// float4 (ds_write_b128 / ds_read_b128, program-ordered within the wave, asm
// clobber pins compiler order). Wave-boundary: float4 ring, write->read always
// >=1 barrier apart (barrier every KB=8 steps). Diet vs R7: scalar DS ops ->
// b128, pf-cndmasks removed (clamped addresses only; out-of-range prefetches
// are provably unused), y pad 16B-per-64B (aligned, conflict-free), pointer
// preselects hoisted.

#define N     4096
#define TPB   512
#define C     4
#define NCH   (N / C)          // 1024 chunks
#define KB    8
#define RSZ   32
#define NW    (TPB / 64)       // 8 waves
#define BIG   1e30f
#define STEPS 1592             // last active step = 567 + 1023 = 1590
#define YIDX4(c) (((c) << 2) + (((c) >> 2) << 2))   // chunk c -> float index

__global__ __launch_bounds__(TPB, 1)
void dtw_diet(const float* __restrict__ xg, const float* __restrict__ yg,
              float* __restrict__ out) {
    __shared__ float  ylds[N + N / 4 + 4];     // 20 KB, padded 16B per 64B
    __shared__ float4 bot4[2][TPB];            // 16 KB double-buffered handoff
    __shared__ float4 ring4[NW - 1][RSZ];      // 3.5 KB wave-boundary rings
    __shared__ float4 bigv;                    // constant {BIG,BIG,BIG,BIG}

    const int t = threadIdx.x, lane = t & 63, w = t >> 6;

    // stage y (coalesced b128 in, padded b128-aligned layout)
    for (int j4 = t * 4; j4 < N; j4 += TPB * 4)
        *(float4*)&ylds[YIDX4(j4 >> 2)] = *(const float4*)&yg[j4];
    if (t == 0) bigv = make_float4(BIG, BIG, BIG, BIG);

    float x[8], carry[8];
    const int i0 = t * 8;
#pragma unroll
    for (int r = 0; r < 8; ++r) { x[r] = xg[i0 + r]; carry[r] = BIG; }

    // diag carry D[i0-1][c*C-1]; (0,0): min3(BIG,BIG,0)=0 -> D[0][0]=c[0][0]
    float diagc = (t == 0) ? 0.0f : BIG;
    const int start = t + KB * w;

    // per-thread-constant routing
    const bool wring = (lane == 63) && (w < NW - 1);   // my bottoms go to ring
    const int  tm1   = (t > 0) ? t - 1 : 0;

    __syncthreads();

    // primed operands for step 0 (only thread 0 is active at step 0)
    float4 nb4 = make_float4(BIG, BIG, BIG, BIG);
    float4 yv  = *(const float4*)&ylds[0];

    for (int sb = 0; sb < STEPS; sb += KB) {
        for (int ss = 0; ss < KB; ++ss) {
            const int s = sb + ss;
            const int c = s - start;

            if ((unsigned)c < (unsigned)NCH) {
                float bt0, bt1, bt2, bt3;
#define DO_COL(YC, NB, DG, BT)                                            \
                { float up = (NB), dgv = (DG);                            \
                  _Pragma("unroll")                                       \
                  for (int r = 0; r < 8; ++r) {                           \
                      const float old = carry[r];                         \
                      const float v = fabsf(x[r] - (YC)) +                \
                                      fminf(up, fminf(old, dgv));         \
                      carry[r] = v; up = v; dgv = old;                    \
                  }                                                       \
                  (BT) = up; }
                DO_COL(yv.x, nb4.x, diagc, bt0)
                DO_COL(yv.y, nb4.y, nb4.x, bt1)
                DO_COL(yv.z, nb4.z, nb4.y, bt2)
                DO_COL(yv.w, nb4.w, nb4.z, bt3)
#undef DO_COL
                diagc = nb4.w;

                float4* wp = wring ? &ring4[w][c & (RSZ - 1)]
                                   : &bot4[s & 1][t];
                *wp = make_float4(bt0, bt1, bt2, bt3);
            }

            // ---- tail prefetch for step s+1 (chunk c1 = c+1) ----
            // No value-masks: out-of-range prefetches are unused (body guarded),
            // only addresses are clamped. Thread 0 reads the constant bigv.
            {
                const int c1 = c + 1;
                const float4* rp;
                if (lane == 0)
                    rp = (w == 0) ? &bigv : &ring4[w - 1][c1 & (RSZ - 1)];
                else
                    rp = &bot4[s & 1][tm1];
                nb4 = *rp;
                int cc = c1 < 0 ? 0 : (c1 > NCH - 1 ? NCH - 1 : c1);
                yv = *(const float4*)&ylds[YIDX4(cc)];
            }
            asm volatile("" ::: "memory");   // pin DS op order across steps
        }
        __syncthreads();   // epoch barrier: orders all ring traffic
    }

    // D[N-1][N-1]: thread TPB-1, row 7
    if (t == TPB - 1) out[0] = carry[7];
}

extern "C" void kernel_launch(void* const* d_in, const int* in_sizes, int n_in,
                              void* d_out, int out_size, void* d_ws, size_t ws_size,
                              hipStream_t stream) {
    const float* src = (const float*)d_in[0];
    const float* tgt = (const float*)d_in[1];
    float* out = (float*)d_out;
    hipLaunchKernelGGL(dtw_diet, dim3(1), dim3(TPB), 0, stream, src, tgt, out);
}